// Round 10
// baseline (210.677 us; speedup 1.0000x reference)
//
#include <hip/hip_runtime.h>
#include <hip/hip_bf16.h>

#define N_NODES 50000
#define N_EDGES 500000
#define D_IN    128
#define D_K     384
#define D_OUT   128
#define BN_EPS  1e-5f
#define N_TASK  (2 * N_NODES)   // recv tasks then send tasks
#define CAP     64              // bucket capacity (max degree ~30 for Poisson(10))
#define NBX     ((N_NODES + 255) / 256)    // 196 gemm x-blocks (256 nodes each)
#define PSTRIDE 200                        // padded partial stride (>= NBX)

typedef __bf16 bf16x8 __attribute__((ext_vector_type(8)));
typedef __bf16 bf16x4 __attribute__((ext_vector_type(4)));
typedef float  f32x4  __attribute__((ext_vector_type(4)));

// ---- workspace layout (bytes) ----
#define OFF_AGG   0ULL           // bf16 [2][50000][128] = 25,600,000
#define OFF_CNT   25600000ULL    // int  [100000]        =    400,000
#define OFF_EID   26000000ULL    // int  [100000][64]    = 25,600,000
#define OFF_PSTAT 51600000ULL    // f32  [256][200]      =    204,800
#define OFF_SCALE 51804800ULL
#define OFF_SHIFT 51805312ULL
#define OFF_HB    51805824ULL    // bf16 [50000][128]    = 12,800,000

// ---------------- bucket CSR build: count + place in one pass ----------------
__global__ __launch_bounds__(256) void bucket_kernel(const int* __restrict__ row,
                                                     const int* __restrict__ col,
                                                     int* __restrict__ cnt,
                                                     int* __restrict__ eid) {
    int i = blockIdx.x * blockDim.x + threadIdx.x;
    if (i < N_EDGES) {
        const int c = col[i];
        const int r = atomicAdd(&cnt[c], 1);
        if (r < CAP) eid[(size_t)c * CAP + r] = i;
        const int rw = row[i];
        const int r2 = atomicAdd(&cnt[N_NODES + rw], 1);
        if (r2 < CAP) eid[((size_t)N_NODES + rw) * CAP + r2] = i;
    }
}

// ---------------- gather-sum: one HALF-WAVE per (node, side) task ----------------
// One eid load per task (single chained latency), then up to 32 predicated
// independent row-loads (f32x4/lane, 512B/row) issued back-to-back.
__global__ __launch_bounds__(256) void gather_kernel(const float* __restrict__ edge_attr,
                                                     const int* __restrict__ cnt,
                                                     const int* __restrict__ eid,
                                                     __bf16* __restrict__ agg) {
    const int hl  = threadIdx.x & 31;                 // lane in half-wave
    const int hwv = (threadIdx.x >> 5) & 1;           // half index within wave
    const int wid = blockIdx.x * 8 + (threadIdx.x >> 5);
    const int n   = min(cnt[wid], CAP);
    const size_t beg = (size_t)wid * CAP;
    const int c   = hl * 4;                           // channel base
    f32x4 acc0 = (f32x4)0.0f, acc1 = (f32x4)0.0f;

    const int e_reg = (hl < n) ? eid[beg + hl] : 0;
#pragma unroll
    for (int j = 0; j < 32; ++j) {
        const int e = __shfl(e_reg, hwv * 32 + j);
        if (j < n) {
            const f32x4 v = *(const f32x4*)(edge_attr + (size_t)e * D_IN + c);
            if (j & 1) acc1 += v; else acc0 += v;
        }
    }
    if (__builtin_expect(n > 32, 0)) {   // essentially never for Poisson(10)
        for (int cb = 32; cb < n; cb += 32) {
            const int m2 = n - cb;
            const int e2 = (hl < m2) ? eid[beg + cb + hl] : 0;
#pragma unroll
            for (int j = 0; j < 32; ++j) {
                const int e = __shfl(e2, hwv * 32 + j);
                if (j < m2) {
                    const f32x4 v = *(const f32x4*)(edge_attr + (size_t)e * D_IN + c);
                    if (j & 1) acc1 += v; else acc0 += v;
                }
            }
        }
    }
    acc0 += acc1;

    bf16x4 o;
#pragma unroll
    for (int q = 0; q < 4; ++q) o[q] = (__bf16)acc0[q];
    *(bf16x4*)(agg + (size_t)wid * D_IN + c) = o;
}

// ---------------- fused GEMM + bias + ReLU + BN-partials ----------------
// grid (NBX, 2): blockIdx.y = channel half (64 ch). W-half staged f32->bf16 into
// LDS (XOR-swizzled). Block = 8 waves; wave w -> nodes [bx*256 + w*32, +32).
// h stored bf16; per-channel stats exit as per-block partials (f32, exact acc).
#define ROW_B 768   // bytes per W row in LDS (384 * 2)
__global__ __launch_bounds__(512) void gemm_kernel(
    const __bf16* __restrict__ agg, const float* __restrict__ node_attr,
    const float* __restrict__ W, const float* __restrict__ bias,
    __bf16* __restrict__ hb, float* __restrict__ pstat) {
    __shared__ __align__(16) char Ws[64 * ROW_B];   // 49152 B
    __shared__ float sred[2][8][64];                // +4096 B

    const int lane = threadIdx.x & 63;
    const int w    = threadIdx.x >> 6;
    const int m    = lane & 15;   // A-row / C-col lane index
    const int g    = lane >> 4;   // k-group
    const int cy   = blockIdx.y;  // channel half

    // ---- stage W-half into LDS (f32 -> bf16), swizzled: byte ^= ((row&7)<<4) ----
    {
        const float* src = W + (size_t)cy * 64 * D_K;
#pragma unroll
        for (int i = 0; i < 6; ++i) {
            const int idx = i * 512 + threadIdx.x;        // vec16 index, 3072 total
            const int r   = idx / 48;                     // 48 vec16 per row
            const int c8  = idx % 48;                     // 8-elem group in row
            const float* p = src + (size_t)r * D_K + c8 * 8;
            f32x4 v0 = *(const f32x4*)p, v1 = *(const f32x4*)(p + 4);
            bf16x8 v;
#pragma unroll
            for (int q = 0; q < 4; ++q) { v[q] = (__bf16)v0[q]; v[q + 4] = (__bf16)v1[q]; }
            *(bf16x8*)(Ws + r * ROW_B + ((c8 * 16) ^ ((r & 7) << 4))) = v;
        }
    }
    __syncthreads();

    const int nodeA0 = blockIdx.x * 256 + w * 32 + m;
    const int nodeA1 = nodeA0 + 16;

    f32x4 acc[2][4];
#pragma unroll
    for (int i = 0; i < 2; ++i)
#pragma unroll
        for (int f = 0; f < 4; ++f) acc[i][f] = (f32x4)0.0f;

#pragma unroll
    for (int ks = 0; ks < 12; ++ks) {
        const int k0 = ks * 32;
        bf16x8 a0, a1;
#pragma unroll
        for (int i = 0; i < 8; ++i) { a0[i] = (__bf16)0.0f; a1[i] = (__bf16)0.0f; }
        if (ks < 8) {   // recv/send stored bf16
            const size_t base = (size_t)(k0 >> 7) * (N_NODES * D_IN) + (k0 & 127) + g * 8;
            if (nodeA0 < N_NODES) a0 = *(const bf16x8*)(agg + base + (size_t)nodeA0 * D_IN);
            if (nodeA1 < N_NODES) a1 = *(const bf16x8*)(agg + base + (size_t)nodeA1 * D_IN);
        } else {        // node_attr f32 -> bf16
            const size_t base = (k0 - 256) + g * 8;
            if (nodeA0 < N_NODES) {
                const float* p = node_attr + (size_t)nodeA0 * D_IN + base;
                f32x4 v0 = *(const f32x4*)p, v1 = *(const f32x4*)(p + 4);
#pragma unroll
                for (int i = 0; i < 4; ++i) { a0[i] = (__bf16)v0[i]; a0[i + 4] = (__bf16)v1[i]; }
            }
            if (nodeA1 < N_NODES) {
                const float* p = node_attr + (size_t)nodeA1 * D_IN + base;
                f32x4 v0 = *(const f32x4*)p, v1 = *(const f32x4*)(p + 4);
#pragma unroll
                for (int i = 0; i < 4; ++i) { a1[i] = (__bf16)v0[i]; a1[i + 4] = (__bf16)v1[i]; }
            }
        }
#pragma unroll
        for (int f = 0; f < 4; ++f) {
            const int r = f * 16 + m;
            const int cb = (k0 + g * 8) * 2;
            bf16x8 bfrag = *(const bf16x8*)(Ws + r * ROW_B + (cb ^ ((r & 7) << 4)));
            acc[0][f] = __builtin_amdgcn_mfma_f32_16x16x32_bf16(a0, bfrag, acc[0][f], 0, 0, 0);
            acc[1][f] = __builtin_amdgcn_mfma_f32_16x16x32_bf16(a1, bfrag, acc[1][f], 0, 0, 0);
        }
    }

    // epilogue: bias + relu + write h (bf16) + per-wave channel stats into LDS
#pragma unroll
    for (int f = 0; f < 4; ++f) {
        const int j  = cy * 64 + f * 16 + m;
        const float bj = bias[j];
        float s1 = 0.0f, s2 = 0.0f;
#pragma unroll
        for (int i = 0; i < 2; ++i) {
#pragma unroll
            for (int r = 0; r < 4; ++r) {
                const int nodeC = blockIdx.x * 256 + w * 32 + i * 16 + g * 4 + r;
                float v = acc[i][f][r] + bj;
                v = v > 0.0f ? v : 0.0f;
                if (nodeC < N_NODES) {
                    hb[(size_t)nodeC * D_OUT + j] = (__bf16)v;
                    s1 += v;
                    s2 += v * v;
                }
            }
        }
        s1 += __shfl_xor(s1, 16, 64);  s2 += __shfl_xor(s2, 16, 64);
        s1 += __shfl_xor(s1, 32, 64);  s2 += __shfl_xor(s2, 32, 64);
        if (lane < 16) { sred[0][w][f * 16 + m] = s1; sred[1][w][f * 16 + m] = s2; }
    }
    __syncthreads();
    if (threadIdx.x < 128) {
        const int s = threadIdx.x >> 6;
        const int c = threadIdx.x & 63;
        float v = 0.0f;
#pragma unroll
        for (int q = 0; q < 8; ++q) v += sred[s][q][c];
        pstat[(size_t)(s * 128 + cy * 64 + c) * PSTRIDE + blockIdx.x] = v;
    }
}

// ---------------- BN finalize: reduce partials + scale/shift ----------------
__global__ __launch_bounds__(256) void bn_finalize_kernel(
    const float* __restrict__ pstat, const float* __restrict__ gamma,
    const float* __restrict__ beta, float* __restrict__ scale, float* __restrict__ shift) {
    const int j = blockIdx.x;   // channel 0..127
    float a1 = 0.0f, a2 = 0.0f;
    for (int b = threadIdx.x; b < NBX; b += 256) {
        a1 += pstat[(size_t)j * PSTRIDE + b];
        a2 += pstat[(size_t)(128 + j) * PSTRIDE + b];
    }
#pragma unroll
    for (int ofs = 32; ofs >= 1; ofs >>= 1) {
        a1 += __shfl_xor(a1, ofs, 64);
        a2 += __shfl_xor(a2, ofs, 64);
    }
    __shared__ float w1[4], w2[4];
    if ((threadIdx.x & 63) == 0) { w1[threadIdx.x >> 6] = a1; w2[threadIdx.x >> 6] = a2; }
    __syncthreads();
    if (threadIdx.x == 0) {
        const float S1 = w1[0] + w1[1] + w1[2] + w1[3];
        const float S2 = w2[0] + w2[1] + w2[2] + w2[3];
        const float inv_n = 1.0f / (float)N_NODES;
        const float mu  = S1 * inv_n;
        const float var = S2 * inv_n - mu * mu;
        const float sc  = gamma[j] * rsqrtf(var + BN_EPS);
        scale[j] = sc;
        shift[j] = beta[j] - mu * sc;
    }
}

// ---------------- BN apply: read bf16 h, write f32 out ----------------
__global__ __launch_bounds__(256) void bn_apply_kernel(
    const __bf16* __restrict__ hb, float* __restrict__ out,
    const float* __restrict__ scale, const float* __restrict__ shift) {
    size_t i = ((size_t)blockIdx.x * blockDim.x + threadIdx.x) * 8;
    if (i >= (size_t)N_NODES * D_OUT) return;
    const int j0 = (int)(i & 127);
    bf16x8 v = *(const bf16x8*)(hb + i);
    f32x4 a, b;
#pragma unroll
    for (int q = 0; q < 4; ++q) {
        a[q] = (float)v[q]     * scale[j0 + q]     + shift[j0 + q];
        b[q] = (float)v[q + 4] * scale[j0 + 4 + q] + shift[j0 + 4 + q];
    }
    *(f32x4*)(out + i)     = a;
    *(f32x4*)(out + i + 4) = b;
}

extern "C" void kernel_launch(void* const* d_in, const int* in_sizes, int n_in,
                              void* d_out, int out_size, void* d_ws, size_t ws_size,
                              hipStream_t stream) {
    const float* edge_attr = (const float*)d_in[0];
    const float* node_attr = (const float*)d_in[1];
    const float* W         = (const float*)d_in[2];
    const float* bias      = (const float*)d_in[3];
    const float* gamma     = (const float*)d_in[4];
    const float* beta      = (const float*)d_in[5];
    const int*   row       = (const int*)d_in[6];
    const int*   col       = (const int*)d_in[7];
    float* out = (float*)d_out;

    char* ws = (char*)d_ws;
    __bf16* agg   = (__bf16*)(ws + OFF_AGG);
    int*    cnt   = (int*)(ws + OFF_CNT);
    int*    eid   = (int*)(ws + OFF_EID);
    float*  pstat = (float*)(ws + OFF_PSTAT);
    float*  scale = (float*)(ws + OFF_SCALE);
    float*  shift = (float*)(ws + OFF_SHIFT);
    __bf16* hb    = (__bf16*)(ws + OFF_HB);

    hipMemsetAsync(cnt, 0, N_TASK * sizeof(int), stream);

    bucket_kernel<<<(N_EDGES + 255) / 256, 256, 0, stream>>>(row, col, cnt, eid);
    gather_kernel<<<N_TASK / 8, 256, 0, stream>>>(edge_attr, cnt, eid, agg);
    dim3 ggrid(NBX, 2);
    gemm_kernel<<<ggrid, 512, 0, stream>>>(agg, node_attr, W, bias, hb, pstat);
    bn_finalize_kernel<<<128, 256, 0, stream>>>(pstat, gamma, beta, scale, shift);
    bn_apply_kernel<<<(N_NODES * D_OUT / 8 + 255) / 256, 256, 0, stream>>>(hb, out, scale, shift);
}

// Round 11
// 205.292 us; speedup vs baseline: 1.0262x; 1.0262x over previous
//
#include <hip/hip_runtime.h>
#include <hip/hip_bf16.h>

#define N_NODES 50000
#define N_EDGES 500000
#define D_IN    128
#define D_K     384
#define D_OUT   128
#define BN_EPS  1e-5f
#define N_TASK  (2 * N_NODES)   // recv tasks then send tasks
#define CAP     64              // bucket capacity (max degree ~30 for Poisson(10))
#define NBX     ((N_NODES + 255) / 256)    // 196 gemm x-blocks (256 nodes each)
#define PSTRIDE 200                        // padded partial stride (>= NBX)

typedef __bf16 bf16x8 __attribute__((ext_vector_type(8)));
typedef __bf16 bf16x4 __attribute__((ext_vector_type(4)));
typedef float  f32x4  __attribute__((ext_vector_type(4)));

// ---- workspace layout (bytes) ----
#define OFF_AGG   0ULL           // bf16 [2][50000][128] = 25,600,000
#define OFF_CNT   25600000ULL    // int  [100000]        =    400,000
#define OFF_EID   26000000ULL    // int  [100000][64]    = 25,600,000
#define OFF_PSTAT 51600000ULL    // f32  [256][200]      =    204,800
#define OFF_SCALE 51804800ULL
#define OFF_SHIFT 51805312ULL
#define OFF_HB    51805824ULL    // bf16 [50000][128]    = 12,800,000

// ---------------- bucket CSR build: count + place in one pass ----------------
__global__ __launch_bounds__(256) void bucket_kernel(const int* __restrict__ row,
                                                     const int* __restrict__ col,
                                                     int* __restrict__ cnt,
                                                     int* __restrict__ eid) {
    int i = blockIdx.x * blockDim.x + threadIdx.x;
    if (i < N_EDGES) {
        const int c = col[i];
        const int r = atomicAdd(&cnt[c], 1);
        if (r < CAP) eid[(size_t)c * CAP + r] = i;
        const int rw = row[i];
        const int r2 = atomicAdd(&cnt[N_NODES + rw], 1);
        if (r2 < CAP) eid[((size_t)N_NODES + rw) * CAP + r2] = i;
    }
}

// ---------------- gather-sum: one HALF-WAVE per (node, side) task ----------------
// Key fix (R11): 8 edge rows loaded into an EXPLICIT v[8] register array with a
// sched_barrier between loads and adds -> compiler must keep 8 loads in flight
// (R10 had VGPR_Count=16: only ~2 loads outstanding, latency-serialized).
__global__ __launch_bounds__(256) void gather_kernel(const float* __restrict__ edge_attr,
                                                     const int* __restrict__ cnt,
                                                     const int* __restrict__ eid,
                                                     __bf16* __restrict__ agg) {
    const int hl  = threadIdx.x & 31;                 // lane in half-wave
    const int hwv = (threadIdx.x >> 5) & 1;           // half index within wave
    const int wid = blockIdx.x * 8 + (threadIdx.x >> 5);
    const int n   = min(cnt[wid], CAP);
    const size_t beg = (size_t)wid * CAP;
    const int c   = hl * 4;                           // channel base
    f32x4 acc0 = (f32x4)0.0f, acc1 = (f32x4)0.0f,
          acc2 = (f32x4)0.0f, acc3 = (f32x4)0.0f;

    const int e_reg = (hl < n) ? eid[beg + hl] : 0;   // lanes >= n broadcast edge 0
    const int nn = min(n, 32);
    for (int base = 0; base < nn; base += 8) {
        f32x4 v0, v1, v2, v3, v4, v5, v6, v7;
        {
            const int b = base;
            v0 = *(const f32x4*)(edge_attr + (size_t)__shfl(e_reg, hwv * 32 + ((b + 0) & 31)) * D_IN + c);
            v1 = *(const f32x4*)(edge_attr + (size_t)__shfl(e_reg, hwv * 32 + ((b + 1) & 31)) * D_IN + c);
            v2 = *(const f32x4*)(edge_attr + (size_t)__shfl(e_reg, hwv * 32 + ((b + 2) & 31)) * D_IN + c);
            v3 = *(const f32x4*)(edge_attr + (size_t)__shfl(e_reg, hwv * 32 + ((b + 3) & 31)) * D_IN + c);
            v4 = *(const f32x4*)(edge_attr + (size_t)__shfl(e_reg, hwv * 32 + ((b + 4) & 31)) * D_IN + c);
            v5 = *(const f32x4*)(edge_attr + (size_t)__shfl(e_reg, hwv * 32 + ((b + 5) & 31)) * D_IN + c);
            v6 = *(const f32x4*)(edge_attr + (size_t)__shfl(e_reg, hwv * 32 + ((b + 6) & 31)) * D_IN + c);
            v7 = *(const f32x4*)(edge_attr + (size_t)__shfl(e_reg, hwv * 32 + ((b + 7) & 31)) * D_IN + c);
        }
        __builtin_amdgcn_sched_barrier(0);   // all 8 loads issued before any add
        if (base + 0 < n) acc0 += v0;
        if (base + 1 < n) acc1 += v1;
        if (base + 2 < n) acc2 += v2;
        if (base + 3 < n) acc3 += v3;
        if (base + 4 < n) acc0 += v4;
        if (base + 5 < n) acc1 += v5;
        if (base + 6 < n) acc2 += v6;
        if (base + 7 < n) acc3 += v7;
    }
    if (__builtin_expect(n > 32, 0)) {       // essentially never for Poisson(10)
        const int e2 = (32 + hl < n) ? eid[beg + 32 + hl] : 0;
        for (int base = 32; base < n; base += 8) {
            f32x4 v0, v1, v2, v3, v4, v5, v6, v7;
            const int b = base - 32;
            v0 = *(const f32x4*)(edge_attr + (size_t)__shfl(e2, hwv * 32 + ((b + 0) & 31)) * D_IN + c);
            v1 = *(const f32x4*)(edge_attr + (size_t)__shfl(e2, hwv * 32 + ((b + 1) & 31)) * D_IN + c);
            v2 = *(const f32x4*)(edge_attr + (size_t)__shfl(e2, hwv * 32 + ((b + 2) & 31)) * D_IN + c);
            v3 = *(const f32x4*)(edge_attr + (size_t)__shfl(e2, hwv * 32 + ((b + 3) & 31)) * D_IN + c);
            v4 = *(const f32x4*)(edge_attr + (size_t)__shfl(e2, hwv * 32 + ((b + 4) & 31)) * D_IN + c);
            v5 = *(const f32x4*)(edge_attr + (size_t)__shfl(e2, hwv * 32 + ((b + 5) & 31)) * D_IN + c);
            v6 = *(const f32x4*)(edge_attr + (size_t)__shfl(e2, hwv * 32 + ((b + 6) & 31)) * D_IN + c);
            v7 = *(const f32x4*)(edge_attr + (size_t)__shfl(e2, hwv * 32 + ((b + 7) & 31)) * D_IN + c);
            __builtin_amdgcn_sched_barrier(0);
            if (base + 0 < n) acc0 += v0;
            if (base + 1 < n) acc1 += v1;
            if (base + 2 < n) acc2 += v2;
            if (base + 3 < n) acc3 += v3;
            if (base + 4 < n) acc0 += v4;
            if (base + 5 < n) acc1 += v5;
            if (base + 6 < n) acc2 += v6;
            if (base + 7 < n) acc3 += v7;
        }
    }
    acc0 += acc1;  acc2 += acc3;  acc0 += acc2;

    bf16x4 o;
#pragma unroll
    for (int q = 0; q < 4; ++q) o[q] = (__bf16)acc0[q];
    *(bf16x4*)(agg + (size_t)wid * D_IN + c) = o;
}

// ---------------- fused GEMM + bias + ReLU + BN-partials ----------------
// grid (NBX, 2): blockIdx.y = channel half (64 ch). W-half staged f32->bf16 into
// LDS (XOR-swizzled). Block = 8 waves; wave w -> nodes [bx*256 + w*32, +32).
// h stored bf16; per-channel stats exit as per-block partials (f32, exact acc).
#define ROW_B 768   // bytes per W row in LDS (384 * 2)
__global__ __launch_bounds__(512) void gemm_kernel(
    const __bf16* __restrict__ agg, const float* __restrict__ node_attr,
    const float* __restrict__ W, const float* __restrict__ bias,
    __bf16* __restrict__ hb, float* __restrict__ pstat) {
    __shared__ __align__(16) char Ws[64 * ROW_B];   // 49152 B
    __shared__ float sred[2][8][64];                // +4096 B

    const int lane = threadIdx.x & 63;
    const int w    = threadIdx.x >> 6;
    const int m    = lane & 15;   // A-row / C-col lane index
    const int g    = lane >> 4;   // k-group
    const int cy   = blockIdx.y;  // channel half

    // ---- stage W-half into LDS (f32 -> bf16), swizzled: byte ^= ((row&7)<<4) ----
    {
        const float* src = W + (size_t)cy * 64 * D_K;
#pragma unroll
        for (int i = 0; i < 6; ++i) {
            const int idx = i * 512 + threadIdx.x;        // vec16 index, 3072 total
            const int r   = idx / 48;                     // 48 vec16 per row
            const int c8  = idx % 48;                     // 8-elem group in row
            const float* p = src + (size_t)r * D_K + c8 * 8;
            f32x4 v0 = *(const f32x4*)p, v1 = *(const f32x4*)(p + 4);
            bf16x8 v;
#pragma unroll
            for (int q = 0; q < 4; ++q) { v[q] = (__bf16)v0[q]; v[q + 4] = (__bf16)v1[q]; }
            *(bf16x8*)(Ws + r * ROW_B + ((c8 * 16) ^ ((r & 7) << 4))) = v;
        }
    }
    __syncthreads();

    const int nodeA0 = blockIdx.x * 256 + w * 32 + m;
    const int nodeA1 = nodeA0 + 16;

    f32x4 acc[2][4];
#pragma unroll
    for (int i = 0; i < 2; ++i)
#pragma unroll
        for (int f = 0; f < 4; ++f) acc[i][f] = (f32x4)0.0f;

#pragma unroll
    for (int ks = 0; ks < 12; ++ks) {
        const int k0 = ks * 32;
        bf16x8 a0, a1;
#pragma unroll
        for (int i = 0; i < 8; ++i) { a0[i] = (__bf16)0.0f; a1[i] = (__bf16)0.0f; }
        if (ks < 8) {   // recv/send stored bf16
            const size_t base = (size_t)(k0 >> 7) * (N_NODES * D_IN) + (k0 & 127) + g * 8;
            if (nodeA0 < N_NODES) a0 = *(const bf16x8*)(agg + base + (size_t)nodeA0 * D_IN);
            if (nodeA1 < N_NODES) a1 = *(const bf16x8*)(agg + base + (size_t)nodeA1 * D_IN);
        } else {        // node_attr f32 -> bf16
            const size_t base = (k0 - 256) + g * 8;
            if (nodeA0 < N_NODES) {
                const float* p = node_attr + (size_t)nodeA0 * D_IN + base;
                f32x4 v0 = *(const f32x4*)p, v1 = *(const f32x4*)(p + 4);
#pragma unroll
                for (int i = 0; i < 4; ++i) { a0[i] = (__bf16)v0[i]; a0[i + 4] = (__bf16)v1[i]; }
            }
            if (nodeA1 < N_NODES) {
                const float* p = node_attr + (size_t)nodeA1 * D_IN + base;
                f32x4 v0 = *(const f32x4*)p, v1 = *(const f32x4*)(p + 4);
#pragma unroll
                for (int i = 0; i < 4; ++i) { a1[i] = (__bf16)v0[i]; a1[i + 4] = (__bf16)v1[i]; }
            }
        }
#pragma unroll
        for (int f = 0; f < 4; ++f) {
            const int r = f * 16 + m;
            const int cb = (k0 + g * 8) * 2;
            bf16x8 bfrag = *(const bf16x8*)(Ws + r * ROW_B + (cb ^ ((r & 7) << 4)));
            acc[0][f] = __builtin_amdgcn_mfma_f32_16x16x32_bf16(a0, bfrag, acc[0][f], 0, 0, 0);
            acc[1][f] = __builtin_amdgcn_mfma_f32_16x16x32_bf16(a1, bfrag, acc[1][f], 0, 0, 0);
        }
    }

    // epilogue: bias + relu + write h (bf16) + per-wave channel stats into LDS
#pragma unroll
    for (int f = 0; f < 4; ++f) {
        const int j  = cy * 64 + f * 16 + m;
        const float bj = bias[j];
        float s1 = 0.0f, s2 = 0.0f;
#pragma unroll
        for (int i = 0; i < 2; ++i) {
#pragma unroll
            for (int r = 0; r < 4; ++r) {
                const int nodeC = blockIdx.x * 256 + w * 32 + i * 16 + g * 4 + r;
                float v = acc[i][f][r] + bj;
                v = v > 0.0f ? v : 0.0f;
                if (nodeC < N_NODES) {
                    hb[(size_t)nodeC * D_OUT + j] = (__bf16)v;
                    s1 += v;
                    s2 += v * v;
                }
            }
        }
        s1 += __shfl_xor(s1, 16, 64);  s2 += __shfl_xor(s2, 16, 64);
        s1 += __shfl_xor(s1, 32, 64);  s2 += __shfl_xor(s2, 32, 64);
        if (lane < 16) { sred[0][w][f * 16 + m] = s1; sred[1][w][f * 16 + m] = s2; }
    }
    __syncthreads();
    if (threadIdx.x < 128) {
        const int s = threadIdx.x >> 6;
        const int c = threadIdx.x & 63;
        float v = 0.0f;
#pragma unroll
        for (int q = 0; q < 8; ++q) v += sred[s][q][c];
        pstat[(size_t)(s * 128 + cy * 64 + c) * PSTRIDE + blockIdx.x] = v;
    }
}

// ---------------- BN finalize: reduce partials + scale/shift ----------------
__global__ __launch_bounds__(256) void bn_finalize_kernel(
    const float* __restrict__ pstat, const float* __restrict__ gamma,
    const float* __restrict__ beta, float* __restrict__ scale, float* __restrict__ shift) {
    const int j = blockIdx.x;   // channel 0..127
    float a1 = 0.0f, a2 = 0.0f;
    for (int b = threadIdx.x; b < NBX; b += 256) {
        a1 += pstat[(size_t)j * PSTRIDE + b];
        a2 += pstat[(size_t)(128 + j) * PSTRIDE + b];
    }
#pragma unroll
    for (int ofs = 32; ofs >= 1; ofs >>= 1) {
        a1 += __shfl_xor(a1, ofs, 64);
        a2 += __shfl_xor(a2, ofs, 64);
    }
    __shared__ float w1[4], w2[4];
    if ((threadIdx.x & 63) == 0) { w1[threadIdx.x >> 6] = a1; w2[threadIdx.x >> 6] = a2; }
    __syncthreads();
    if (threadIdx.x == 0) {
        const float S1 = w1[0] + w1[1] + w1[2] + w1[3];
        const float S2 = w2[0] + w2[1] + w2[2] + w2[3];
        const float inv_n = 1.0f / (float)N_NODES;
        const float mu  = S1 * inv_n;
        const float var = S2 * inv_n - mu * mu;
        const float sc  = gamma[j] * rsqrtf(var + BN_EPS);
        scale[j] = sc;
        shift[j] = beta[j] - mu * sc;
    }
}

// ---------------- BN apply: read bf16 h, write f32 out ----------------
__global__ __launch_bounds__(256) void bn_apply_kernel(
    const __bf16* __restrict__ hb, float* __restrict__ out,
    const float* __restrict__ scale, const float* __restrict__ shift) {
    size_t i = ((size_t)blockIdx.x * blockDim.x + threadIdx.x) * 8;
    if (i >= (size_t)N_NODES * D_OUT) return;
    const int j0 = (int)(i & 127);
    bf16x8 v = *(const bf16x8*)(hb + i);
    f32x4 a, b;
#pragma unroll
    for (int q = 0; q < 4; ++q) {
        a[q] = (float)v[q]     * scale[j0 + q]     + shift[j0 + q];
        b[q] = (float)v[q + 4] * scale[j0 + 4 + q] + shift[j0 + 4 + q];
    }
    *(f32x4*)(out + i)     = a;
    *(f32x4*)(out + i + 4) = b;
}

extern "C" void kernel_launch(void* const* d_in, const int* in_sizes, int n_in,
                              void* d_out, int out_size, void* d_ws, size_t ws_size,
                              hipStream_t stream) {
    const float* edge_attr = (const float*)d_in[0];
    const float* node_attr = (const float*)d_in[1];
    const float* W         = (const float*)d_in[2];
    const float* bias      = (const float*)d_in[3];
    const float* gamma     = (const float*)d_in[4];
    const float* beta      = (const float*)d_in[5];
    const int*   row       = (const int*)d_in[6];
    const int*   col       = (const int*)d_in[7];
    float* out = (float*)d_out;

    char* ws = (char*)d_ws;
    __bf16* agg   = (__bf16*)(ws + OFF_AGG);
    int*    cnt   = (int*)(ws + OFF_CNT);
    int*    eid   = (int*)(ws + OFF_EID);
    float*  pstat = (float*)(ws + OFF_PSTAT);
    float*  scale = (float*)(ws + OFF_SCALE);
    float*  shift = (float*)(ws + OFF_SHIFT);
    __bf16* hb    = (__bf16*)(ws + OFF_HB);

    hipMemsetAsync(cnt, 0, N_TASK * sizeof(int), stream);

    bucket_kernel<<<(N_EDGES + 255) / 256, 256, 0, stream>>>(row, col, cnt, eid);
    gather_kernel<<<N_TASK / 8, 256, 0, stream>>>(edge_attr, cnt, eid, agg);
    dim3 ggrid(NBX, 2);
    gemm_kernel<<<ggrid, 512, 0, stream>>>(agg, node_attr, W, bias, hb, pstat);
    bn_finalize_kernel<<<128, 256, 0, stream>>>(pstat, gamma, beta, scale, shift);
    bn_apply_kernel<<<(N_NODES * D_OUT / 8 + 255) / 256, 256, 0, stream>>>(hb, out, scale, shift);
}